// Round 5
// baseline (391.676 us; speedup 1.0000x reference)
//
#include <hip/hip_runtime.h>
#include <hip/hip_fp16.h>
#include <stdint.h>

// Atten_L: B=2, L=64, C=256, S=256, D=512. fp32 I/O, fp16 MFMA compute.
// R5 (3rd resubmit; three straight broker/container infra failures, kernel
// has never run): occupancy fix for the two remaining GEMMs. R1 rocprof:
// proj3 = 149us, MfmaUtil 14%, VALUBusy 14%, occupancy 28%, bank-conflict 0
// -> latency-bound (barrier drains with ~9 waves/CU resident; acc[4][4]=64
// AGPR + pre[8]=32 VGPR capped residency). proj3 and gemm_out use 512
// threads / 8 waves per 128x128 tile (wave tile 64x32, acc[4][2]=32 AGPR,
// pre[4]): ~2x resident waves -> barrier drains overlap across waves.
// attn_fused unchanged (passed on HW in R1, byte-identical).

typedef _Float16 f16;
typedef __attribute__((ext_vector_type(8))) _Float16 f16x8;
typedef __attribute__((ext_vector_type(4))) _Float16 f16x4;
typedef __attribute__((ext_vector_type(4))) float f32x4;

#define BK 64

__device__ __forceinline__ void glds16(const void* g, void* l)
{
    __builtin_amdgcn_global_load_lds(
        (const __attribute__((address_space(1))) void*)(uintptr_t)g,
        (__attribute__((address_space(3))) void*)(uint32_t)(uintptr_t)l,
        16, 0, 0);
}

// ---------------- merged q/k/v projection: 3072 blocks x 512 threads ------
// which = blockIdx>>10 selects (queries->qh), (keys->kh), (values->vT^T).
__global__ __launch_bounds__(512)
void proj3(const float* __restrict__ qin, const float* __restrict__ kin,
           const float* __restrict__ vin, const f16* __restrict__ wq,
           const f16* __restrict__ wkv, const float* __restrict__ bq,
           const float* __restrict__ bkv, f16* __restrict__ qh,
           f16* __restrict__ kh, f16* __restrict__ vT)
{
    __shared__ f16 As[128][64];
    __shared__ f16 Bs[128][64];

    const int p     = blockIdx.x;
    const int which = p >> 10;
    const int inner = p & 1023;
    const int xcd   = inner & 7;
    const int slot  = inner >> 3;
    const int m0 = (xcd + 8 * (slot >> 2)) * 128;
    const int n0 = (slot & 3) * 128;

    const float* A    = (which == 0) ? qin : (which == 1) ? kin : vin;
    const f16*   Bt   = (which == 0) ? wq : wkv;
    const float* bias = (which == 0) ? bq : bkv;

    const int tid  = threadIdx.x;
    const int lane = tid & 63;
    const int wave = tid >> 6;         // 0..7
    const int quad = lane >> 4;
    const int l16  = lane & 15;
    const int wr   = wave >> 2;        // 0..1 row half (64 rows)
    const int wc   = wave & 3;         // 0..3 col quarter (32 cols)

    f32x4 acc[4][2];
    #pragma unroll
    for (int i = 0; i < 4; ++i)
        #pragma unroll
        for (int j = 0; j < 2; ++j)
            acc[i][j] = (f32x4){0.f, 0.f, 0.f, 0.f};

    const int i8 = lane >> 3;
    const int cl = (((lane & 7) - i8) & 7) * 8;

    // A staging (fp32 -> f16, reg path): thread owns row ar, 16 cols at ac
    const int ar = tid >> 2;           // 0..127
    const int ac = (tid & 3) * 16;     // 0,16,32,48

    float4 pre[4];
    auto load_a = [&](int k0) {
        const float* s = A + (long)(m0 + ar) * 512 + k0 + ac;
        pre[0] = ((const float4*)s)[0];
        pre[1] = ((const float4*)s)[1];
        pre[2] = ((const float4*)s)[2];
        pre[3] = ((const float4*)s)[3];
    };
    auto store_a = [&]() {
        const int rot = (ar & 7) * 8;
        f16x8 v0, v1;
        v0[0] = (f16)pre[0].x; v0[1] = (f16)pre[0].y;
        v0[2] = (f16)pre[0].z; v0[3] = (f16)pre[0].w;
        v0[4] = (f16)pre[1].x; v0[5] = (f16)pre[1].y;
        v0[6] = (f16)pre[1].z; v0[7] = (f16)pre[1].w;
        v1[0] = (f16)pre[2].x; v1[1] = (f16)pre[2].y;
        v1[2] = (f16)pre[2].z; v1[3] = (f16)pre[2].w;
        v1[4] = (f16)pre[3].x; v1[5] = (f16)pre[3].y;
        v1[6] = (f16)pre[3].z; v1[7] = (f16)pre[3].w;
        *(f16x8*)&As[ar][(ac + rot) & 63]     = v0;
        *(f16x8*)&As[ar][(ac + 8 + rot) & 63] = v1;
    };

    for (int k0 = 0; k0 < 512; k0 += BK) {
        if (k0 == 0) load_a(0);
        if (k0) __syncthreads();
        #pragma unroll
        for (int g = 0; g < 2; ++g) {        // Bs: 16 row-groups / 8 waves
            const int R0 = (wave * 2 + g) * 8;
            glds16(Bt + (long)(n0 + R0 + i8) * 512 + k0 + cl, &Bs[R0][0]);
        }
        store_a();
        __syncthreads();
        if (k0 + BK < 512) load_a(k0 + BK);

        #pragma unroll
        for (int ksub = 0; ksub < 2; ++ksub) {
            f16x8 af[4], bf[2];
            #pragma unroll
            for (int i = 0; i < 4; ++i) {
                const int r  = wr * 64 + i * 16 + l16;
                const int pc = ((ksub * 32 + quad * 8) + ((r & 7) * 8)) & 63;
                af[i] = *(const f16x8*)&As[r][pc];
            }
            #pragma unroll
            for (int j = 0; j < 2; ++j) {
                const int r  = wc * 32 + j * 16 + l16;
                const int pc = ((ksub * 32 + quad * 8) + ((r & 7) * 8)) & 63;
                bf[j] = *(const f16x8*)&Bs[r][pc];
            }
            #pragma unroll
            for (int i = 0; i < 4; ++i)
                #pragma unroll
                for (int j = 0; j < 2; ++j)
                    acc[i][j] = __builtin_amdgcn_mfma_f32_16x16x32_f16(
                        af[i], bf[j], acc[i][j], 0, 0, 0);
        }
    }

    f16* qout = (which == 0) ? qh : kh;
    #pragma unroll
    for (int i = 0; i < 4; ++i) {
        #pragma unroll
        for (int j = 0; j < 2; ++j) {
            const int col = n0 + wc * 32 + j * 16 + l16;
            const float bv = bias[col];
            #pragma unroll
            for (int r = 0; r < 4; ++r) {
                const int row = m0 + wr * 64 + i * 16 + quad * 4 + r;
                const float val = acc[i][j][r] + bv;
                if (which == 2)
                    vT[(long)(row >> 8) * 131072 + (long)col * 256 + (row & 255)] = (f16)val;
                else
                    qout[(long)row * 512 + col] = (f16)val;
            }
        }
    }
}

// ---------------- output projection: 1024 blocks x 512 threads -----------
// out[m][n] = sum_k ao[m][k] * wo[n][k] + bo[n], fp32 out.
__global__ __launch_bounds__(512)
void gemm_out(const f16* __restrict__ Ah, const f16* __restrict__ Bt,
              const float* __restrict__ bias, float* __restrict__ C)
{
    __shared__ f16 As[128][64];
    __shared__ f16 Bs[128][64];

    const int p    = blockIdx.x;
    const int xcd  = p & 7;
    const int slot = p >> 3;
    const int m0 = (xcd + 8 * (slot >> 2)) * 128;
    const int n0 = (slot & 3) * 128;

    const int tid  = threadIdx.x;
    const int lane = tid & 63;
    const int wave = tid >> 6;
    const int quad = lane >> 4;
    const int l16  = lane & 15;
    const int wr   = wave >> 2;
    const int wc   = wave & 3;

    f32x4 acc[4][2];
    #pragma unroll
    for (int i = 0; i < 4; ++i)
        #pragma unroll
        for (int j = 0; j < 2; ++j)
            acc[i][j] = (f32x4){0.f, 0.f, 0.f, 0.f};

    const int i8 = lane >> 3;
    const int cl = (((lane & 7) - i8) & 7) * 8;

    for (int k0 = 0; k0 < 512; k0 += BK) {
        if (k0) __syncthreads();
        #pragma unroll
        for (int g = 0; g < 2; ++g) {
            const int R0 = (wave * 2 + g) * 8;
            glds16(Ah + (long)(m0 + R0 + i8) * 512 + k0 + cl, &As[R0][0]);
            glds16(Bt + (long)(n0 + R0 + i8) * 512 + k0 + cl, &Bs[R0][0]);
        }
        __syncthreads();

        #pragma unroll
        for (int ksub = 0; ksub < 2; ++ksub) {
            f16x8 af[4], bf[2];
            #pragma unroll
            for (int i = 0; i < 4; ++i) {
                const int r  = wr * 64 + i * 16 + l16;
                const int pc = ((ksub * 32 + quad * 8) + ((r & 7) * 8)) & 63;
                af[i] = *(const f16x8*)&As[r][pc];
            }
            #pragma unroll
            for (int j = 0; j < 2; ++j) {
                const int r  = wc * 32 + j * 16 + l16;
                const int pc = ((ksub * 32 + quad * 8) + ((r & 7) * 8)) & 63;
                bf[j] = *(const f16x8*)&Bs[r][pc];
            }
            #pragma unroll
            for (int i = 0; i < 4; ++i)
                #pragma unroll
                for (int j = 0; j < 2; ++j)
                    acc[i][j] = __builtin_amdgcn_mfma_f32_16x16x32_f16(
                        af[i], bf[j], acc[i][j], 0, 0, 0);
        }
    }

    #pragma unroll
    for (int i = 0; i < 4; ++i) {
        #pragma unroll
        for (int j = 0; j < 2; ++j) {
            const int col = n0 + wc * 32 + j * 16 + l16;
            const float bv = bias[col];
            #pragma unroll
            for (int r = 0; r < 4; ++r) {
                const int row = m0 + wr * 64 + i * 16 + quad * 4 + r;
                C[(long)row * 512 + col] = acc[i][j][r] + bv;
            }
        }
    }
}

// ---------------- fused QK^T + softmax + PV (unchanged this round) --------
__global__ __launch_bounds__(512)
void attn_fused(const f16* __restrict__ q, const f16* __restrict__ k,
                const f16* __restrict__ vT, f16* __restrict__ O)
{
    __shared__ __align__(16) f16 bufA[128 * 256];   // 64KB: As+Bs, then Ps
    __shared__ __align__(16) f16 Vs[4][128][64];    // 64KB: V^T panel
    __shared__ float red[2][128][4];                //  4KB

    f16 (*As)[BK]  = (f16(*)[BK])bufA;              // [128][64]
    f16 (*Bs)[BK]  = (f16(*)[BK])(bufA + 128 * 64); // [256][64]
    f16 (*Ps)[256] = (f16(*)[256])bufA;             // [128][256]

    const int p    = blockIdx.x;
    const int xcd  = p & 7;
    const int slot = p >> 3;
    const int z    = xcd + 8 * (slot >> 1);
    const int m0   = (slot & 1) * 128;

    const int tid  = threadIdx.x;
    const int lane = tid & 63;
    const int wave = tid >> 6;
    const int quad = lane >> 4;
    const int l16  = lane & 15;
    const int wr   = wave >> 2;        // 0..1 row half
    const int wc   = wave & 3;         // 0..3 col quarter

    const f16* Aq = q  + (long)z * 131072 + (long)m0 * 512;
    const f16* Bk = k  + (long)z * 131072;
    const f16* Vt = vT + (long)z * 131072;

    f32x4 acc[4][4];
    #pragma unroll
    for (int i = 0; i < 4; ++i)
        #pragma unroll
        for (int j = 0; j < 4; ++j)
            acc[i][j] = (f32x4){0.f, 0.f, 0.f, 0.f};

    const int i8 = lane >> 3;
    const int cl = (((lane & 7) - i8) & 7) * 8;

    // ---- stage 1: S = Q K^T ----
    for (int k0 = 0; k0 < 512; k0 += BK) {
        if (k0) __syncthreads();
        #pragma unroll
        for (int g = 0; g < 2; ++g) {
            const int R0 = (wave * 2 + g) * 8;
            glds16(Aq + (long)(R0 + i8) * 512 + k0 + cl, &As[R0][0]);
        }
        #pragma unroll
        for (int g = 0; g < 4; ++g) {
            const int R0 = (wave * 4 + g) * 8;
            glds16(Bk + (long)(R0 + i8) * 512 + k0 + cl, &Bs[R0][0]);
        }
        __syncthreads();

        #pragma unroll
        for (int ksub = 0; ksub < 2; ++ksub) {
            f16x8 af[4], bf[4];
            #pragma unroll
            for (int i = 0; i < 4; ++i) {
                const int r  = wr * 64 + i * 16 + l16;
                const int pc = ((ksub * 32 + quad * 8) + ((r & 7) * 8)) & 63;
                af[i] = *(const f16x8*)&As[r][pc];
            }
            #pragma unroll
            for (int j = 0; j < 4; ++j) {
                const int r  = wc * 64 + j * 16 + l16;
                const int pc = ((ksub * 32 + quad * 8) + ((r & 7) * 8)) & 63;
                bf[j] = *(const f16x8*)&Bs[r][pc];
            }
            #pragma unroll
            for (int i = 0; i < 4; ++i)
                #pragma unroll
                for (int j = 0; j < 4; ++j)
                    acc[i][j] = __builtin_amdgcn_mfma_f32_16x16x32_f16(
                        af[i], bf[j], acc[i][j], 0, 0, 0);
        }
    }

    // ---- softmax (rows of 256) ----
    const float scale = 0.044194173824159216f;  // 1/sqrt(512)
    float st[4][4];
    #pragma unroll
    for (int i = 0; i < 4; ++i)
        #pragma unroll
        for (int r = 0; r < 4; ++r) {
            float m = acc[i][0][r];
            #pragma unroll
            for (int j = 1; j < 4; ++j) m = fmaxf(m, acc[i][j][r]);
            st[i][r] = m;
        }
    #pragma unroll
    for (int off = 1; off < 16; off <<= 1)
        #pragma unroll
        for (int i = 0; i < 4; ++i)
            #pragma unroll
            for (int r = 0; r < 4; ++r)
                st[i][r] = fmaxf(st[i][r], __shfl_xor(st[i][r], off, 64));
    if (l16 == 0)
        #pragma unroll
        for (int i = 0; i < 4; ++i)
            #pragma unroll
            for (int r = 0; r < 4; ++r)
                red[0][wr * 64 + i * 16 + quad * 4 + r][wc] = st[i][r];
    __syncthreads();   // also: last As/Bs reads done -> bufA reusable as Ps

    // exp (unnormalized, e<=1) -> Ps (swizzled); local sums
    #pragma unroll
    for (int i = 0; i < 4; ++i)
        #pragma unroll
        for (int r = 0; r < 4; ++r) {
            const int row = wr * 64 + i * 16 + quad * 4 + r;
            const float m = fmaxf(fmaxf(red[0][row][0], red[0][row][1]),
                                  fmaxf(red[0][row][2], red[0][row][3]));
            float s = 0.f;
            #pragma unroll
            for (int j = 0; j < 4; ++j) {
                const float e = __expf(scale * (acc[i][j][r] - m));
                s += e;
                const int col = wc * 64 + j * 16 + l16;
                Ps[row][(col & 192) + (((col & 63) + ((row & 7) * 8)) & 63)] = (f16)e;
            }
            st[i][r] = s;
        }
    #pragma unroll
    for (int off = 1; off < 16; off <<= 1)
        #pragma unroll
        for (int i = 0; i < 4; ++i)
            #pragma unroll
            for (int r = 0; r < 4; ++r)
                st[i][r] += __shfl_xor(st[i][r], off, 64);
    if (l16 == 0)
        #pragma unroll
        for (int i = 0; i < 4; ++i)
            #pragma unroll
            for (int r = 0; r < 4; ++r)
                red[1][wr * 64 + i * 16 + quad * 4 + r][wc] = st[i][r];
    __syncthreads();

    if (tid < 128) {
        const float s = red[1][tid][0] + red[1][tid][1] +
                        red[1][tid][2] + red[1][tid][3];
        red[0][tid][0] = 1.0f / s;
    }

    // ---- stage 2: O = P V  (M=128, N=512, K=256; P entirely in LDS) ----
    for (int nc = 0; nc < 4; ++nc) {
        const int n0c = nc * 128;
        __syncthreads();
        #pragma unroll
        for (int kb = 0; kb < 4; ++kb)
            #pragma unroll
            for (int g = 0; g < 2; ++g) {
                const int R0 = (wave * 2 + g) * 8;
                glds16(Vt + (long)(n0c + R0 + i8) * 256 + kb * 64 + cl,
                       &Vs[kb][R0][0]);
            }
        __syncthreads();

        f32x4 acc2[4][2];
        #pragma unroll
        for (int i = 0; i < 4; ++i)
            #pragma unroll
            for (int j = 0; j < 2; ++j)
                acc2[i][j] = (f32x4){0.f, 0.f, 0.f, 0.f};

        #pragma unroll
        for (int kb = 0; kb < 4; ++kb)
            #pragma unroll
            for (int ksub = 0; ksub < 2; ++ksub) {
                f16x8 af[4], bf[2];
                #pragma unroll
                for (int i = 0; i < 4; ++i) {
                    const int r  = wr * 64 + i * 16 + l16;
                    const int pc = kb * 64 +
                        (((ksub * 32 + quad * 8) + ((r & 7) * 8)) & 63);
                    af[i] = *(const f16x8*)&Ps[r][pc];
                }
                #pragma unroll
                for (int j = 0; j < 2; ++j) {
                    const int rv = wc * 32 + j * 16 + l16;
                    const int pc = ((ksub * 32 + quad * 8) + ((rv & 7) * 8)) & 63;
                    bf[j] = *(const f16x8*)&Vs[kb][rv][pc];
                }
                #pragma unroll
                for (int i = 0; i < 4; ++i)
                    #pragma unroll
                    for (int j = 0; j < 2; ++j)
                        acc2[i][j] = __builtin_amdgcn_mfma_f32_16x16x32_f16(
                            af[i], bf[j], acc2[i][j], 0, 0, 0);
            }

        #pragma unroll
        for (int i = 0; i < 4; ++i)
            #pragma unroll
            for (int j = 0; j < 2; ++j) {
                const int col = n0c + wc * 32 + j * 16 + l16;
                #pragma unroll
                for (int rr = 0; rr < 4; ++rr) {
                    const int row = wr * 64 + i * 16 + quad * 4 + rr;
                    const float inv = red[0][row][0];
                    O[(long)z * 131072 + (long)(m0 + row) * 512 + col] =
                        (f16)(acc2[i][j][rr] * inv);
                }
            }
    }
}

__global__ __launch_bounds__(256)
void cvt3(const float* __restrict__ a, const float* __restrict__ b,
          const float* __restrict__ c, f16* __restrict__ oa,
          f16* __restrict__ ob, f16* __restrict__ oc)
{
    const int w = blockIdx.x >> 8;
    const int t = ((blockIdx.x & 255) * 256 + threadIdx.x) * 4;
    const float* src = (w == 0) ? a : (w == 1) ? b : c;
    f16* dst = (w == 0) ? oa : (w == 1) ? ob : oc;
    const float4 v = *(const float4*)(src + t);
    f16x4 o;
    o[0] = (f16)v.x; o[1] = (f16)v.y; o[2] = (f16)v.z; o[3] = (f16)v.w;
    *(f16x4*)(dst + t) = o;
}

extern "C" void kernel_launch(void* const* d_in, const int* in_sizes, int n_in,
                              void* d_out, int out_size, void* d_ws, size_t ws_size,
                              hipStream_t stream)
{
    const float* queries = (const float*)d_in[0];
    const float* keys    = (const float*)d_in[1];
    const float* values  = (const float*)d_in[2];
    const float* Wq      = (const float*)d_in[3];
    const float* bq      = (const float*)d_in[4];
    const float* Wkv     = (const float*)d_in[5];
    const float* bkv     = (const float*)d_in[6];
    const float* Wo      = (const float*)d_in[7];
    const float* bo      = (const float*)d_in[8];
    float* out = (float*)d_out;

    // f16 workspace layout (~96 MB + weights):
    f16* ws  = (f16*)d_ws;
    f16* wq  = ws;                      //   262144
    f16* wkv = ws + 262144;
    f16* wo  = ws + 524288;
    f16* qh  = ws + 786432;             // 32 MB  q  (ao overlays after attn)
    f16* kh  = qh + 16777216;           // 32 MB  k
    f16* vT  = kh + 16777216;           // 32 MB  v^T
    f16* ao  = qh;                      // overlay: block writes only rows it
                                        // alone reads, after its last read

    cvt3<<<768, 256, 0, stream>>>(Wq, Wkv, Wo, wq, wkv, wo);

    proj3<<<3072, dim3(512), 0, stream>>>(
        queries, keys, values, wq, wkv, bq, bkv, qh, kh, vT);

    attn_fused<<<256, 512, 0, stream>>>(qh, kh, vT, ao);

    gemm_out<<<1024, dim3(512), 0, stream>>>(ao, wo, bo, out);
}

// Round 6
// 360.024 us; speedup vs baseline: 1.0879x; 1.0879x over previous
//
#include <hip/hip_runtime.h>
#include <hip/hip_fp16.h>
#include <stdint.h>

// Atten_L: B=2, L=64, C=256, S=256, D=512. fp32 I/O, fp16 MFMA compute.
// R6: post-mortem of R5 (512-thr blocks REGRESSED 149->180us despite
// occupancy 28->42%: barrier-locked waves don't hide drains, independent
// blocks do, and blocks/CU fell 2.25->1.67). Revised theory: proj3's stall
// is the serial A-staging chain (fp32 load->reg->cvt->ds_write) inside the
// barrier interval. Fix: A staged via async global_load_lds as RAW FP32
// (32KB LDS tile, 16B-granule rotation swizzle keyed on row&7, pre-swizzled
// global source + linear DMA dest), f32->f16 cvt moved to fragment-read
// time. Both operands now async DMA = the verified m97 structure. Back to
// 256 thr / 4 waves / acc[4][4]. gemm_out reverted to R1-proven 256-thr.
// attn_fused unchanged (HW-proven).

typedef _Float16 f16;
typedef __attribute__((ext_vector_type(8))) _Float16 f16x8;
typedef __attribute__((ext_vector_type(4))) _Float16 f16x4;
typedef __attribute__((ext_vector_type(4))) float f32x4;

#define BK 64

__device__ __forceinline__ void glds16(const void* g, void* l)
{
    __builtin_amdgcn_global_load_lds(
        (const __attribute__((address_space(1))) void*)(uintptr_t)g,
        (__attribute__((address_space(3))) void*)(uint32_t)(uintptr_t)l,
        16, 0, 0);
}

// ---------------- merged q/k/v projection: 3072 blocks x 256 threads ------
// which = blockIdx>>10 selects (queries->qh), (keys->kh), (values->vT^T).
// A (fp32) staged via glds16 into Asf[128][64] f32 (granule-rotation
// swizzle); B (f16 weights) staged via glds16 as before. cvt at frag read.
__global__ __launch_bounds__(256)
void proj3(const float* __restrict__ qin, const float* __restrict__ kin,
           const float* __restrict__ vin, const f16* __restrict__ wq,
           const f16* __restrict__ wkv, const float* __restrict__ bq,
           const float* __restrict__ bkv, f16* __restrict__ qh,
           f16* __restrict__ kh, f16* __restrict__ vT)
{
    __shared__ __align__(16) float Asf[128][64];   // 32KB fp32 A tile
    __shared__ __align__(16) f16  Bs[128][64];     // 16KB f16 weights

    const int p     = blockIdx.x;
    const int which = p >> 10;
    const int inner = p & 1023;
    const int xcd   = inner & 7;
    const int slot  = inner >> 3;
    const int m0 = (xcd + 8 * (slot >> 2)) * 128;
    const int n0 = (slot & 3) * 128;

    const float* A    = (which == 0) ? qin : (which == 1) ? kin : vin;
    const f16*   Bt   = (which == 0) ? wq : wkv;
    const float* bias = (which == 0) ? bq : bkv;

    const int tid  = threadIdx.x;
    const int lane = tid & 63;
    const int wave = tid >> 6;         // 0..3
    const int quad = lane >> 4;
    const int l16  = lane & 15;
    const int wr   = wave >> 1;        // 0..1 (64-row half)
    const int wc   = wave & 1;         // 0..1 (64-col half)

    f32x4 acc[4][4];
    #pragma unroll
    for (int i = 0; i < 4; ++i)
        #pragma unroll
        for (int j = 0; j < 4; ++j)
            acc[i][j] = (f32x4){0.f, 0.f, 0.f, 0.f};

    // B staging geometry (granule = 8 f16 = 16B, 8 granules/row)
    const int i8 = lane >> 3;                       // row within 8-row group
    const int cl = (((lane & 7) - i8) & 7) * 8;     // pre-swizzled src col

    // A staging geometry (granule = 4 f32 = 16B, 16 granules/row;
    // one glds16 call covers 4 rows: lane>>4 = row-in-group, lane&15 = dst granule)
    const int ar4 = lane >> 4;

    for (int k0 = 0; k0 < 512; k0 += BK) {
        if (k0) __syncthreads();
        #pragma unroll
        for (int g = 0; g < 8; ++g) {              // A: 32 calls / 4 waves
            const int R0  = (wave * 8 + g) * 4;
            const int row = R0 + ar4;
            const int gcol = ((lane & 15) - (row & 7)) & 15;  // pre-swizzle
            glds16(A + (long)(m0 + row) * 512 + k0 + gcol * 4, &Asf[R0][0]);
        }
        #pragma unroll
        for (int g = 0; g < 4; ++g) {              // B: 16 calls / 4 waves
            const int R0 = (wave * 4 + g) * 8;
            glds16(Bt + (long)(n0 + R0 + i8) * 512 + k0 + cl, &Bs[R0][0]);
        }
        __syncthreads();

        #pragma unroll
        for (int ksub = 0; ksub < 2; ++ksub) {
            f16x8 af[4], bf[4];
            #pragma unroll
            for (int i = 0; i < 4; ++i) {
                const int r  = wr * 64 + i * 16 + l16;
                const int g0 = ksub * 8 + quad * 2;           // logical granule
                const int ga = (g0 + (r & 7)) & 15;           // swizzled
                const int gb = (g0 + 1 + (r & 7)) & 15;
                const f32x4 a0 = *(const f32x4*)&Asf[r][ga * 4];
                const f32x4 a1 = *(const f32x4*)&Asf[r][gb * 4];
                f16x8 v;
                v[0] = (f16)a0[0]; v[1] = (f16)a0[1];
                v[2] = (f16)a0[2]; v[3] = (f16)a0[3];
                v[4] = (f16)a1[0]; v[5] = (f16)a1[1];
                v[6] = (f16)a1[2]; v[7] = (f16)a1[3];
                af[i] = v;
            }
            #pragma unroll
            for (int j = 0; j < 4; ++j) {
                const int r  = wc * 64 + j * 16 + l16;
                const int pc = ((ksub * 32 + quad * 8) + ((r & 7) * 8)) & 63;
                bf[j] = *(const f16x8*)&Bs[r][pc];
            }
            #pragma unroll
            for (int i = 0; i < 4; ++i)
                #pragma unroll
                for (int j = 0; j < 4; ++j)
                    acc[i][j] = __builtin_amdgcn_mfma_f32_16x16x32_f16(
                        af[i], bf[j], acc[i][j], 0, 0, 0);
        }
    }

    f16* qout = (which == 0) ? qh : kh;
    #pragma unroll
    for (int i = 0; i < 4; ++i) {
        #pragma unroll
        for (int j = 0; j < 4; ++j) {
            const int col = n0 + wc * 64 + j * 16 + l16;
            const float bv = bias[col];
            #pragma unroll
            for (int r = 0; r < 4; ++r) {
                const int row = m0 + wr * 64 + i * 16 + quad * 4 + r;
                const float val = acc[i][j][r] + bv;
                if (which == 2)
                    vT[(long)(row >> 8) * 131072 + (long)col * 256 + (row & 255)] = (f16)val;
                else
                    qout[(long)row * 512 + col] = (f16)val;
            }
        }
    }
}

// ---------------- output projection: 1024 blocks x 256 threads (R1 cfg) ---
// out[m][n] = sum_k ao[m][k] * wo[n][k] + bo[n], fp32 out.
__global__ __launch_bounds__(256)
void gemm_out(const f16* __restrict__ Ah, const f16* __restrict__ Bt,
              const float* __restrict__ bias, float* __restrict__ C)
{
    __shared__ f16 As[128][64];
    __shared__ f16 Bs[128][64];

    const int p    = blockIdx.x;
    const int xcd  = p & 7;
    const int slot = p >> 3;
    const int m0 = (xcd + 8 * (slot >> 2)) * 128;
    const int n0 = (slot & 3) * 128;

    const int tid  = threadIdx.x;
    const int lane = tid & 63;
    const int wave = tid >> 6;
    const int quad = lane >> 4;
    const int l16  = lane & 15;
    const int wr   = wave >> 1;
    const int wc   = wave & 1;

    f32x4 acc[4][4];
    #pragma unroll
    for (int i = 0; i < 4; ++i)
        #pragma unroll
        for (int j = 0; j < 4; ++j)
            acc[i][j] = (f32x4){0.f, 0.f, 0.f, 0.f};

    const int i8 = lane >> 3;
    const int cl = (((lane & 7) - i8) & 7) * 8;

    for (int k0 = 0; k0 < 512; k0 += BK) {
        if (k0) __syncthreads();
        #pragma unroll
        for (int j = 0; j < 4; ++j) {
            const int R0 = (wave * 4 + j) * 8;
            glds16(Ah + (long)(m0 + R0 + i8) * 512 + k0 + cl, &As[R0][0]);
            glds16(Bt + (long)(n0 + R0 + i8) * 512 + k0 + cl, &Bs[R0][0]);
        }
        __syncthreads();

        #pragma unroll
        for (int ksub = 0; ksub < 2; ++ksub) {
            f16x8 af[4], bf[4];
            #pragma unroll
            for (int i = 0; i < 4; ++i) {
                const int r  = wr * 64 + i * 16 + l16;
                const int pc = ((ksub * 32 + quad * 8) + ((r & 7) * 8)) & 63;
                af[i] = *(const f16x8*)&As[r][pc];
            }
            #pragma unroll
            for (int j = 0; j < 4; ++j) {
                const int r  = wc * 64 + j * 16 + l16;
                const int pc = ((ksub * 32 + quad * 8) + ((r & 7) * 8)) & 63;
                bf[j] = *(const f16x8*)&Bs[r][pc];
            }
            #pragma unroll
            for (int i = 0; i < 4; ++i)
                #pragma unroll
                for (int j = 0; j < 4; ++j)
                    acc[i][j] = __builtin_amdgcn_mfma_f32_16x16x32_f16(
                        af[i], bf[j], acc[i][j], 0, 0, 0);
        }
    }

    #pragma unroll
    for (int i = 0; i < 4; ++i) {
        #pragma unroll
        for (int j = 0; j < 4; ++j) {
            const int col = n0 + wc * 64 + j * 16 + l16;
            const float bv = bias[col];
            #pragma unroll
            for (int r = 0; r < 4; ++r) {
                const int row = m0 + wr * 64 + i * 16 + quad * 4 + r;
                C[(long)row * 512 + col] = acc[i][j][r] + bv;
            }
        }
    }
}

// ---------------- fused QK^T + softmax + PV (unchanged, HW-proven) --------
__global__ __launch_bounds__(512)
void attn_fused(const f16* __restrict__ q, const f16* __restrict__ k,
                const f16* __restrict__ vT, f16* __restrict__ O)
{
    __shared__ __align__(16) f16 bufA[128 * 256];   // 64KB: As+Bs, then Ps
    __shared__ __align__(16) f16 Vs[4][128][64];    // 64KB: V^T panel
    __shared__ float red[2][128][4];                //  4KB

    f16 (*As)[BK]  = (f16(*)[BK])bufA;              // [128][64]
    f16 (*Bs)[BK]  = (f16(*)[BK])(bufA + 128 * 64); // [256][64]
    f16 (*Ps)[256] = (f16(*)[256])bufA;             // [128][256]

    const int p    = blockIdx.x;
    const int xcd  = p & 7;
    const int slot = p >> 3;
    const int z    = xcd + 8 * (slot >> 1);
    const int m0   = (slot & 1) * 128;

    const int tid  = threadIdx.x;
    const int lane = tid & 63;
    const int wave = tid >> 6;
    const int quad = lane >> 4;
    const int l16  = lane & 15;
    const int wr   = wave >> 2;        // 0..1 row half
    const int wc   = wave & 3;         // 0..3 col quarter

    const f16* Aq = q  + (long)z * 131072 + (long)m0 * 512;
    const f16* Bk = k  + (long)z * 131072;
    const f16* Vt = vT + (long)z * 131072;

    f32x4 acc[4][4];
    #pragma unroll
    for (int i = 0; i < 4; ++i)
        #pragma unroll
        for (int j = 0; j < 4; ++j)
            acc[i][j] = (f32x4){0.f, 0.f, 0.f, 0.f};

    const int i8 = lane >> 3;
    const int cl = (((lane & 7) - i8) & 7) * 8;

    // ---- stage 1: S = Q K^T ----
    for (int k0 = 0; k0 < 512; k0 += BK) {
        if (k0) __syncthreads();
        #pragma unroll
        for (int g = 0; g < 2; ++g) {
            const int R0 = (wave * 2 + g) * 8;
            glds16(Aq + (long)(R0 + i8) * 512 + k0 + cl, &As[R0][0]);
        }
        #pragma unroll
        for (int g = 0; g < 4; ++g) {
            const int R0 = (wave * 4 + g) * 8;
            glds16(Bk + (long)(R0 + i8) * 512 + k0 + cl, &Bs[R0][0]);
        }
        __syncthreads();

        #pragma unroll
        for (int ksub = 0; ksub < 2; ++ksub) {
            f16x8 af[4], bf[4];
            #pragma unroll
            for (int i = 0; i < 4; ++i) {
                const int r  = wr * 64 + i * 16 + l16;
                const int pc = ((ksub * 32 + quad * 8) + ((r & 7) * 8)) & 63;
                af[i] = *(const f16x8*)&As[r][pc];
            }
            #pragma unroll
            for (int j = 0; j < 4; ++j) {
                const int r  = wc * 64 + j * 16 + l16;
                const int pc = ((ksub * 32 + quad * 8) + ((r & 7) * 8)) & 63;
                bf[j] = *(const f16x8*)&Bs[r][pc];
            }
            #pragma unroll
            for (int i = 0; i < 4; ++i)
                #pragma unroll
                for (int j = 0; j < 4; ++j)
                    acc[i][j] = __builtin_amdgcn_mfma_f32_16x16x32_f16(
                        af[i], bf[j], acc[i][j], 0, 0, 0);
        }
    }

    // ---- softmax (rows of 256) ----
    const float scale = 0.044194173824159216f;  // 1/sqrt(512)
    float st[4][4];
    #pragma unroll
    for (int i = 0; i < 4; ++i)
        #pragma unroll
        for (int r = 0; r < 4; ++r) {
            float m = acc[i][0][r];
            #pragma unroll
            for (int j = 1; j < 4; ++j) m = fmaxf(m, acc[i][j][r]);
            st[i][r] = m;
        }
    #pragma unroll
    for (int off = 1; off < 16; off <<= 1)
        #pragma unroll
        for (int i = 0; i < 4; ++i)
            #pragma unroll
            for (int r = 0; r < 4; ++r)
                st[i][r] = fmaxf(st[i][r], __shfl_xor(st[i][r], off, 64));
    if (l16 == 0)
        #pragma unroll
        for (int i = 0; i < 4; ++i)
            #pragma unroll
            for (int r = 0; r < 4; ++r)
                red[0][wr * 64 + i * 16 + quad * 4 + r][wc] = st[i][r];
    __syncthreads();   // also: last As/Bs reads done -> bufA reusable as Ps

    // exp (unnormalized, e<=1) -> Ps (swizzled); local sums
    #pragma unroll
    for (int i = 0; i < 4; ++i)
        #pragma unroll
        for (int r = 0; r < 4; ++r) {
            const int row = wr * 64 + i * 16 + quad * 4 + r;
            const float m = fmaxf(fmaxf(red[0][row][0], red[0][row][1]),
                                  fmaxf(red[0][row][2], red[0][row][3]));
            float s = 0.f;
            #pragma unroll
            for (int j = 0; j < 4; ++j) {
                const float e = __expf(scale * (acc[i][j][r] - m));
                s += e;
                const int col = wc * 64 + j * 16 + l16;
                Ps[row][(col & 192) + (((col & 63) + ((row & 7) * 8)) & 63)] = (f16)e;
            }
            st[i][r] = s;
        }
    #pragma unroll
    for (int off = 1; off < 16; off <<= 1)
        #pragma unroll
        for (int i = 0; i < 4; ++i)
            #pragma unroll
            for (int r = 0; r < 4; ++r)
                st[i][r] += __shfl_xor(st[i][r], off, 64);
    if (l16 == 0)
        #pragma unroll
        for (int i = 0; i < 4; ++i)
            #pragma unroll
            for (int r = 0; r < 4; ++r)
                red[1][wr * 64 + i * 16 + quad * 4 + r][wc] = st[i][r];
    __syncthreads();

    if (tid < 128) {
        const float s = red[1][tid][0] + red[1][tid][1] +
                        red[1][tid][2] + red[1][tid][3];
        red[0][tid][0] = 1.0f / s;
    }

    // ---- stage 2: O = P V  (M=128, N=512, K=256; P entirely in LDS) ----
    for (int nc = 0; nc < 4; ++nc) {
        const int n0c = nc * 128;
        __syncthreads();
        #pragma unroll
        for (int kb = 0; kb < 4; ++kb)
            #pragma unroll
            for (int g = 0; g < 2; ++g) {
                const int R0 = (wave * 2 + g) * 8;
                glds16(Vt + (long)(n0c + R0 + i8) * 256 + kb * 64 + cl,
                       &Vs[kb][R0][0]);
            }
        __syncthreads();

        f32x4 acc2[4][2];
        #pragma unroll
        for (int i = 0; i < 4; ++i)
            #pragma unroll
            for (int j = 0; j < 2; ++j)
                acc2[i][j] = (f32x4){0.f, 0.f, 0.f, 0.f};

        #pragma unroll
        for (int kb = 0; kb < 4; ++kb)
            #pragma unroll
            for (int ksub = 0; ksub < 2; ++ksub) {
                f16x8 af[4], bf[2];
                #pragma unroll
                for (int i = 0; i < 4; ++i) {
                    const int r  = wr * 64 + i * 16 + l16;
                    const int pc = kb * 64 +
                        (((ksub * 32 + quad * 8) + ((r & 7) * 8)) & 63);
                    af[i] = *(const f16x8*)&Ps[r][pc];
                }
                #pragma unroll
                for (int j = 0; j < 2; ++j) {
                    const int rv = wc * 32 + j * 16 + l16;
                    const int pc = ((ksub * 32 + quad * 8) + ((rv & 7) * 8)) & 63;
                    bf[j] = *(const f16x8*)&Vs[kb][rv][pc];
                }
                #pragma unroll
                for (int i = 0; i < 4; ++i)
                    #pragma unroll
                    for (int j = 0; j < 2; ++j)
                        acc2[i][j] = __builtin_amdgcn_mfma_f32_16x16x32_f16(
                            af[i], bf[j], acc2[i][j], 0, 0, 0);
            }

        #pragma unroll
        for (int i = 0; i < 4; ++i)
            #pragma unroll
            for (int j = 0; j < 2; ++j) {
                const int col = n0c + wc * 32 + j * 16 + l16;
                #pragma unroll
                for (int rr = 0; rr < 4; ++rr) {
                    const int row = wr * 64 + i * 16 + quad * 4 + rr;
                    const float inv = red[0][row][0];
                    O[(long)z * 131072 + (long)(m0 + row) * 512 + col] =
                        (f16)(acc2[i][j][rr] * inv);
                }
            }
    }
}

__global__ __launch_bounds__(256)
void cvt3(const float* __restrict__ a, const float* __restrict__ b,
          const float* __restrict__ c, f16* __restrict__ oa,
          f16* __restrict__ ob, f16* __restrict__ oc)
{
    const int w = blockIdx.x >> 8;
    const int t = ((blockIdx.x & 255) * 256 + threadIdx.x) * 4;
    const float* src = (w == 0) ? a : (w == 1) ? b : c;
    f16* dst = (w == 0) ? oa : (w == 1) ? ob : oc;
    const float4 v = *(const float4*)(src + t);
    f16x4 o;
    o[0] = (f16)v.x; o[1] = (f16)v.y; o[2] = (f16)v.z; o[3] = (f16)v.w;
    *(f16x4*)(dst + t) = o;
}

extern "C" void kernel_launch(void* const* d_in, const int* in_sizes, int n_in,
                              void* d_out, int out_size, void* d_ws, size_t ws_size,
                              hipStream_t stream)
{
    const float* queries = (const float*)d_in[0];
    const float* keys    = (const float*)d_in[1];
    const float* values  = (const float*)d_in[2];
    const float* Wq      = (const float*)d_in[3];
    const float* bq      = (const float*)d_in[4];
    const float* Wkv     = (const float*)d_in[5];
    const float* bkv     = (const float*)d_in[6];
    const float* Wo      = (const float*)d_in[7];
    const float* bo      = (const float*)d_in[8];
    float* out = (float*)d_out;

    // f16 workspace layout (~96 MB + weights):
    f16* ws  = (f16*)d_ws;
    f16* wq  = ws;                      //   262144
    f16* wkv = ws + 262144;
    f16* wo  = ws + 524288;
    f16* qh  = ws + 786432;             // 32 MB  q  (ao overlays after attn)
    f16* kh  = qh + 16777216;           // 32 MB  k
    f16* vT  = kh + 16777216;           // 32 MB  v^T
    f16* ao  = qh;                      // overlay: block writes only rows it
                                        // alone reads, after its last read

    cvt3<<<768, 256, 0, stream>>>(Wq, Wkv, Wo, wq, wkv, wo);

    proj3<<<3072, dim3(256), 0, stream>>>(
        queries, keys, values, wq, wkv, bq, bkv, qh, kh, vT);

    attn_fused<<<256, 512, 0, stream>>>(qh, kh, vT, ao);

    gemm_out<<<1024, dim3(256), 0, stream>>>(ao, wo, bo, out);
}